// Round 2
// baseline (373.671 us; speedup 1.0000x reference)
//
#include <hip/hip_runtime.h>
#include <hip/hip_bf16.h>

#define BN 16384
#define TT 12
#define MLP 1024
#define ZD 32
#define HD 128
#define KD 1056          // MLP+ZD
#define GN 384           // 3*H
#define WIH_LD 1060      // MLP+ZD+2*NPRED
#define NSG 4
#define DTC 1.6f

typedef __attribute__((ext_vector_type(8))) short short8;
typedef __attribute__((ext_vector_type(4))) short short4_t;
typedef __attribute__((ext_vector_type(4))) float floatx4;
typedef __hip_bfloat16 bf16;

__device__ __forceinline__ float bf2f(bf16 v) { return __bfloat162float(v); }
__device__ __forceinline__ bf16 f2bf(float v) { return __float2bfloat16(v); }
__device__ __forceinline__ short bfbits(float x) {
    bf16 t = __float2bfloat16(x);
    return __builtin_bit_cast(short, t);
}
__device__ __forceinline__ float bfraw2f(unsigned short u) {
    return __uint_as_float(((unsigned int)u) << 16);
}
__device__ __forceinline__ float sigm(float x) { return __fdividef(1.0f, 1.0f + __expf(-x)); }
__device__ __forceinline__ float tanh_f(float x) {
    float t = __expf(-2.0f * x);
    return __fdividef(2.0f, 1.0f + t) - 1.0f;
}

// ---------------------------------------------------------------------------
// dtype-abstracted loads/stores. BF=1: memory is bf16. BF=0: memory is fp32.
// ld8 returns 8 consecutive elements as a bf16 MFMA fragment.
// ---------------------------------------------------------------------------
template<int BF> struct IO;
template<> struct IO<1> {
    static __device__ __forceinline__ float ld(const void* p, size_t i) {
        return bf2f(((const bf16*)p)[i]);
    }
    static __device__ __forceinline__ short8 ld8(const void* p, size_t i) {
        const short* q = (const short*)p + i;       // call sites are 8B-aligned
        short4_t lo = *(const short4_t*)q;
        short4_t hi = *(const short4_t*)(q + 4);
        short8 v;
        v[0]=lo[0]; v[1]=lo[1]; v[2]=lo[2]; v[3]=lo[3];
        v[4]=hi[0]; v[5]=hi[1]; v[6]=hi[2]; v[7]=hi[3];
        return v;
    }
    static __device__ __forceinline__ void st(void* p, size_t i, float v) {
        ((bf16*)p)[i] = f2bf(v);
    }
};
template<> struct IO<0> {
    static __device__ __forceinline__ float ld(const void* p, size_t i) {
        return ((const float*)p)[i];
    }
    static __device__ __forceinline__ short8 ld8(const void* p, size_t i) {
        const float* q = (const float*)p + i;       // call sites are 16B-aligned
        floatx4 f0 = *(const floatx4*)q;
        floatx4 f1 = *(const floatx4*)(q + 4);
        short8 v;
        v[0]=bfbits(f0[0]); v[1]=bfbits(f0[1]); v[2]=bfbits(f0[2]); v[3]=bfbits(f0[3]);
        v[4]=bfbits(f1[0]); v[5]=bfbits(f1[1]); v[6]=bfbits(f1[2]); v[7]=bfbits(f1[3]);
        return v;
    }
    static __device__ __forceinline__ void st(void* p, size_t i, float v) {
        ((float*)p)[i] = v;
    }
};

struct Params {
    const void *lst, *lpos, *enc, *zz, *sg, *fut;
    const int* upd;
    const void *Wdec, *bdec, *Wtv, *btv, *Wih, *bih, *Whh, *bhh;
    const void *Wmu, *bmu, *Wstd, *bstd, *Wsg, *bsg;
    const int* flag;
    void* out;
};

struct __align__(16) SMem {
    bf16 pre[32][512];        // fused pre-GEMM result: [gates_zx | h0] for 32 rows
    bf16 h[32][168];          // cols 0..127 = h; 128..131 = (a0,a1,sg0,sg1); rest 0
    float sgf[NSG][32][2];
    float a0[32][2];
    float muw[4][128];
    float b4[4];
};

// ---------------------------------------------------------------------------
// dtype detector: bf16 words have exponent-pattern bits at [14:8]; fp32 words
// have uniform mantissa bits there. Majority vote over 64 words of enc.
// ---------------------------------------------------------------------------
__global__ void k_detect(const unsigned int* __restrict__ w, int* __restrict__ flag) {
    unsigned int x = w[threadIdx.x];
    unsigned int b = (x >> 8) & 0x7Fu;
    bool looks_bf16 = (b >= 0x38u && b <= 0x41u);
    unsigned long long m = __ballot(looks_bf16);
    if (threadIdx.x == 0) flag[0] = (__popcll(m) >= 32) ? 1 : 0;
}

template<int BF>
__device__ __forceinline__ void body(const Params& p, SMem& s) {
    const int tid = threadIdx.x;
    const int lane = tid & 63;
    const int wav = tid >> 6;         // 0..7
    const int wn = wav & 3;
    const int wm = wav >> 2;          // 0..1
    const int c = lane & 15;
    const int quad = lane >> 4;
    const int rows0 = blockIdx.x * 32;
    const int jb = wn * 32;

    // ---------- P0: fused pre-GEMM ----------
    // wave 'wav' computes all 32 rows x cols [wav*64, wav*64+64) of
    // [W_ih[:, :1056] | W_dec_hidden] @ zx^T   (raw, biases added at consume)
    floatx4 acc2[2][4];
#pragma unroll
    for (int i = 0; i < 2; i++)
#pragma unroll
        for (int j = 0; j < 4; j++) acc2[i][j] = floatx4{0.f, 0.f, 0.f, 0.f};
    const int nb = wav * 64;
    for (int kc = 0; kc < 33; kc++) {
        const int k = kc * 32 + quad * 8;
        short8 af[2], bf8[4];
        if (kc < 32) {
            af[0] = IO<BF>::ld8(p.enc, (size_t)(rows0 + c) * MLP + k);
            af[1] = IO<BF>::ld8(p.enc, (size_t)(rows0 + 16 + c) * MLP + k);
        } else {
            af[0] = IO<BF>::ld8(p.zz, (size_t)(rows0 + c) * ZD + (k - MLP));
            af[1] = IO<BF>::ld8(p.zz, (size_t)(rows0 + 16 + c) * ZD + (k - MLP));
        }
#pragma unroll
        for (int j = 0; j < 4; j++) {
            const int n = nb + j * 16 + c;
            bf8[j] = (n < GN) ? IO<BF>::ld8(p.Wih, (size_t)n * WIH_LD + k)
                              : IO<BF>::ld8(p.Wdec, (size_t)(n - GN) * KD + k);
        }
#pragma unroll
        for (int i = 0; i < 2; i++)
#pragma unroll
            for (int j = 0; j < 4; j++)
                acc2[i][j] = __builtin_amdgcn_mfma_f32_16x16x32_bf16(
                    af[i], bf8[j], acc2[i][j], 0, 0, 0);
    }
#pragma unroll
    for (int i = 0; i < 2; i++)
#pragma unroll
        for (int j = 0; j < 4; j++)
#pragma unroll
            for (int r = 0; r < 4; r++)
                s.pre[i * 16 + quad * 4 + r][nb + j * 16 + c] = f2bf(acc2[i][j][r]);

    // ---------- prologue misc (no s.pre reads before the barrier) ----------
    for (int idx = tid; idx < 32 * 40; idx += 512)
        s.h[idx / 40][128 + (idx % 40)] = f2bf(0.0f);
    {
        int sel = tid >> 7, k = tid & 127;
        s.muw[sel][k] = (sel < 2) ? IO<BF>::ld(p.Wmu, sel * 128 + k)
                                  : IO<BF>::ld(p.Wstd, (sel - 2) * 128 + k);
    }
    if (tid < 4) s.b4[tid] = (tid < 2) ? IO<BF>::ld(p.bmu, tid) : IO<BF>::ld(p.bstd, tid - 2);
    if (tid < 32) {
        const int row = rows0 + tid;
        for (int pp = 0; pp < 2; pp++) {
            float sum = IO<BF>::ld(p.btv, pp);
            for (int f = 0; f < 6; f++)
                sum += IO<BF>::ld(p.lst, (size_t)row * 6 + f) * IO<BF>::ld(p.Wtv, pp * 6 + f);
            s.a0[tid][pp] = sum;
        }
        float px = IO<BF>::ld(p.lpos, (size_t)row * 2);
        float py = IO<BF>::ld(p.lpos, (size_t)row * 2 + 1);
        float prevx = 0.f, prevy = 0.f;
        for (int j = 0; j < NSG; j++) {
            float rx = (IO<BF>::ld(p.sg, ((size_t)row * NSG + j) * 2) - px) * 0.01f;
            float ry = (IO<BF>::ld(p.sg, ((size_t)row * NSG + j) * 2 + 1) - py) * 0.01f;
            float vx = (rx - prevx) * (1.0f / DTC), vy = (ry - prevy) * (1.0f / DTC);
            prevx = rx; prevy = ry;
            float st4[4] = {rx, ry, vx, vy};
            for (int pp = 0; pp < 2; pp++) {
                float sum = IO<BF>::ld(p.bsg, pp);
                for (int f = 0; f < 4; f++) sum += st4[f] * IO<BF>::ld(p.Wsg, pp * 4 + f);
                s.sgf[j][tid][pp] = sum;
            }
        }
    }
    int upd[4];
#pragma unroll
    for (int i = 0; i < 4; i++) upd[i] = p.upd[i];

    // W_hh fragments (step-invariant, register-resident)
    short8 Wb[2][3][4];
    short8 Wb4[2][2];
    float Wa2[2][2], Ws2[2][2], bhh2[2];
#pragma unroll
    for (int jt2 = 0; jt2 < 2; jt2++) {
#pragma unroll
        for (int g = 0; g < 3; g++) {
            const int n = g * 128 + jb + jt2 * 16 + c;
#pragma unroll
            for (int kc = 0; kc < 4; kc++)
                Wb[jt2][g][kc] = IO<BF>::ld8(p.Whh, (size_t)n * HD + kc * 32 + quad * 8);
            if (g < 2) {
                short8 v = {0, 0, 0, 0, 0, 0, 0, 0};
                if (quad == 0) {
                    v[0] = bfbits(IO<BF>::ld(p.Wih, (size_t)n * WIH_LD + KD));
                    v[1] = bfbits(IO<BF>::ld(p.Wih, (size_t)n * WIH_LD + KD + 1));
                    v[2] = bfbits(IO<BF>::ld(p.Wih, (size_t)n * WIH_LD + KD + 2));
                    v[3] = bfbits(IO<BF>::ld(p.Wih, (size_t)n * WIH_LD + KD + 3));
                }
                Wb4[jt2][g] = v;
            }
        }
        const int n2 = 256 + jb + jt2 * 16 + c;
        Wa2[jt2][0] = IO<BF>::ld(p.Wih, (size_t)n2 * WIH_LD + KD);
        Wa2[jt2][1] = IO<BF>::ld(p.Wih, (size_t)n2 * WIH_LD + KD + 1);
        Ws2[jt2][0] = IO<BF>::ld(p.Wih, (size_t)n2 * WIH_LD + KD + 2);
        Ws2[jt2][1] = IO<BF>::ld(p.Wih, (size_t)n2 * WIH_LD + KD + 3);
        bhh2[jt2] = IO<BF>::ld(p.bhh, n2);
    }

    __syncthreads();   // s.pre / misc LDS ready

    // ---------- P1: consume pre-GEMM into registers ----------
    floatx4 gzx[2][3];
#pragma unroll
    for (int jt2 = 0; jt2 < 2; jt2++) {
#pragma unroll
        for (int g = 0; g < 3; g++) {
            const int n = g * 128 + jb + jt2 * 16 + c;
            float bias = IO<BF>::ld(p.bih, n) + ((g < 2) ? IO<BF>::ld(p.bhh, n) : 0.0f);
            floatx4 v;
#pragma unroll
            for (int r = 0; r < 4; r++)
                v[r] = bf2f(s.pre[wm * 16 + quad * 4 + r][n]) + bias;
            gzx[jt2][g] = v;
        }
    }
    float hreg[2][4];
#pragma unroll
    for (int jt2 = 0; jt2 < 2; jt2++) {
        const int hcol = jb + jt2 * 16 + c;
        float bd = IO<BF>::ld(p.bdec, hcol);
#pragma unroll
        for (int r = 0; r < 4; r++) {
            const int row = wm * 16 + quad * 4 + r;
            float hv = bf2f(s.pre[row][GN + hcol]) + bd;
            hreg[jt2][r] = hv;
            s.h[row][hcol] = f2bf(hv);
        }
    }
    __syncthreads();

    // ---------- T loop ----------
    const size_t TB2 = (size_t)TT * BN * 2;
    for (int t = 0; t < TT; t++) {
        if (tid < 32) {
            const int row = rows0 + tid;
            float a0v, a1v;
            if (t == 0) { a0v = s.a0[tid][0]; a1v = s.a0[tid][1]; }
            else {
                a0v = IO<BF>::ld(p.fut, ((size_t)(t - 1) * BN + row) * 6 + 2);
                a1v = IO<BF>::ld(p.fut, ((size_t)(t - 1) * BN + row) * 6 + 3);
            }
            int jj = 0;
            for (int q = 1; q < NSG; q++) if (upd[q] <= t) jj = q;
            s.h[tid][128] = f2bf(a0v);
            s.h[tid][129] = f2bf(a1v);
            s.h[tid][130] = f2bf(s.sgf[jj][tid][0]);
            s.h[tid][131] = f2bf(s.sgf[jj][tid][1]);
        }
        __syncthreads();

        floatx4 acc[2][3];
#pragma unroll
        for (int jt2 = 0; jt2 < 2; jt2++) {
            acc[jt2][0] = gzx[jt2][0];
            acc[jt2][1] = gzx[jt2][1];
            floatx4 bb; bb[0] = bb[1] = bb[2] = bb[3] = bhh2[jt2];
            acc[jt2][2] = bb;
        }
#pragma unroll
        for (int kc = 0; kc < 4; kc++) {
            short8 am = *(const short8*)(&s.h[wm * 16 + c][kc * 32 + quad * 8]);
#pragma unroll
            for (int jt2 = 0; jt2 < 2; jt2++)
#pragma unroll
                for (int g = 0; g < 3; g++)
                    acc[jt2][g] = __builtin_amdgcn_mfma_f32_16x16x32_bf16(
                        am, Wb[jt2][g][kc], acc[jt2][g], 0, 0, 0);
        }
        {
            short8 am4 = *(const short8*)(&s.h[wm * 16 + c][128 + quad * 8]);
#pragma unroll
            for (int jt2 = 0; jt2 < 2; jt2++)
#pragma unroll
                for (int g = 0; g < 2; g++)
                    acc[jt2][g] = __builtin_amdgcn_mfma_f32_16x16x32_bf16(
                        am4, Wb4[jt2][g], acc[jt2][g], 0, 0, 0);
        }
        __syncthreads();

#pragma unroll
        for (int r = 0; r < 4; r++) {
            const int mrow = wm * 16 + quad * 4 + r;
            float a0v = bf2f(s.h[mrow][128]);
            float a1v = bf2f(s.h[mrow][129]);
            float s0v = bf2f(s.h[mrow][130]);
            float s1v = bf2f(s.h[mrow][131]);
#pragma unroll
            for (int jt2 = 0; jt2 < 2; jt2++) {
                float rr = sigm(acc[jt2][0][r]);
                float zg = sigm(acc[jt2][1][r]);
                float tn = a0v * Wa2[jt2][0] + a1v * Wa2[jt2][1]
                         + s0v * Ws2[jt2][0] + s1v * Ws2[jt2][1];
                float narg = gzx[jt2][2][r] + tn + rr * acc[jt2][2][r];
                float nn = tanh_f(narg);
                float hv = nn + zg * (hreg[jt2][r] - nn);
                hreg[jt2][r] = hv;
                s.h[mrow][jb + jt2 * 16 + c] = f2bf(hv);
            }
        }
        __syncthreads();

        if (tid < 128) {
            const int row = tid >> 2;
            const int sel = tid & 3;
            float sum = 0.0f;
#pragma unroll
            for (int k8 = 0; k8 < 16; k8++) {
                short8 hv = *(const short8*)(&s.h[row][k8 * 8]);
#pragma unroll
                for (int u = 0; u < 8; u++)
                    sum += bfraw2f((unsigned short)hv[u]) * s.muw[sel][k8 * 8 + u];
            }
            sum += s.b4[sel];
            const size_t grow = (size_t)rows0 + row;
            if (sel < 2) IO<BF>::st(p.out, ((size_t)t * BN + grow) * 2 + sel, sum);
            else IO<BF>::st(p.out, TB2 + ((size_t)t * BN + grow) * 2 + (sel - 2),
                            __expf(0.5f * sum));
        }
    }
}

__global__ __launch_bounds__(512, 2) void k_main(Params p) {
    __shared__ SMem s;
    if (*p.flag) body<1>(p, s);
    else body<0>(p, s);
}

extern "C" void kernel_launch(void* const* d_in, const int* in_sizes, int n_in,
                              void* d_out, int out_size, void* d_ws, size_t ws_size,
                              hipStream_t stream) {
    Params p;
    p.lst  = d_in[0];
    p.lpos = d_in[1];
    p.enc  = d_in[2];
    p.zz   = d_in[3];
    p.sg   = d_in[4];
    p.fut  = d_in[5];
    p.upd  = (const int*)d_in[6];
    p.Wdec = d_in[7];
    p.bdec = d_in[8];
    p.Wtv  = d_in[9];
    p.btv  = d_in[10];
    p.Wih  = d_in[11];
    p.bih  = d_in[12];
    p.Whh  = d_in[13];
    p.bhh  = d_in[14];
    p.Wmu  = d_in[15];
    p.bmu  = d_in[16];
    p.Wstd = d_in[17];
    p.bstd = d_in[18];
    p.Wsg  = d_in[19];
    p.bsg  = d_in[20];
    p.flag = (const int*)d_ws;
    p.out  = d_out;

    k_detect<<<1, 64, 0, stream>>>((const unsigned int*)d_in[2], (int*)d_ws);
    k_main<<<512, 512, 0, stream>>>(p);
}

// Round 6
// 371.626 us; speedup vs baseline: 1.0055x; 1.0055x over previous
//
#include <hip/hip_runtime.h>
#include <hip/hip_bf16.h>

#define BN 16384
#define TT 12
#define MLP 1024
#define ZD 32
#define HD 128
#define KD 1056          // MLP+ZD
#define GN 384           // 3*H
#define WIH_LD 1060      // MLP+ZD+2*NPRED
#define NSG 4
#define DTC 1.6f

typedef __attribute__((ext_vector_type(8))) short short8;
typedef __attribute__((ext_vector_type(4))) short short4_t;
typedef __attribute__((ext_vector_type(4))) float floatx4;
typedef __hip_bfloat16 bf16;

__device__ __forceinline__ float bf2f(bf16 v) { return __bfloat162float(v); }
__device__ __forceinline__ bf16 f2bf(float v) { return __float2bfloat16(v); }
__device__ __forceinline__ short bfbits(float x) {
    bf16 t = __float2bfloat16(x);
    return __builtin_bit_cast(short, t);
}
__device__ __forceinline__ float bfraw2f(unsigned short u) {
    return __uint_as_float(((unsigned int)u) << 16);
}
__device__ __forceinline__ float sigm(float x) { return __fdividef(1.0f, 1.0f + __expf(-x)); }
__device__ __forceinline__ float tanh_f(float x) {
    float t = __expf(-2.0f * x);
    return __fdividef(2.0f, 1.0f + t) - 1.0f;
}

// ---------------------------------------------------------------------------
// dtype-abstracted loads/stores. BF=1: memory is bf16. BF=0: memory is fp32.
// R2+R5 A/B proved the data is fp32 (BF=0 path passed; forced BF=1 NaN'd).
// ld8 returns 8 consecutive elements as a bf16 MFMA fragment.
// ---------------------------------------------------------------------------
template<int BF> struct IO;
template<> struct IO<1> {
    static __device__ __forceinline__ float ld(const void* p, size_t i) {
        return bf2f(((const bf16*)p)[i]);
    }
    static __device__ __forceinline__ short8 ld8(const void* p, size_t i) {
        const short* q = (const short*)p + i;       // call sites are 8B-aligned
        short4_t lo = *(const short4_t*)q;
        short4_t hi = *(const short4_t*)(q + 4);
        short8 v;
        v[0]=lo[0]; v[1]=lo[1]; v[2]=lo[2]; v[3]=lo[3];
        v[4]=hi[0]; v[5]=hi[1]; v[6]=hi[2]; v[7]=hi[3];
        return v;
    }
    static __device__ __forceinline__ void st(void* p, size_t i, float v) {
        ((bf16*)p)[i] = f2bf(v);
    }
};
template<> struct IO<0> {
    static __device__ __forceinline__ float ld(const void* p, size_t i) {
        return ((const float*)p)[i];
    }
    static __device__ __forceinline__ short8 ld8(const void* p, size_t i) {
        const float* q = (const float*)p + i;       // call sites are 16B-aligned
        floatx4 f0 = *(const floatx4*)q;
        floatx4 f1 = *(const floatx4*)(q + 4);
        short8 v;
        v[0]=bfbits(f0[0]); v[1]=bfbits(f0[1]); v[2]=bfbits(f0[2]); v[3]=bfbits(f0[3]);
        v[4]=bfbits(f1[0]); v[5]=bfbits(f1[1]); v[6]=bfbits(f1[2]); v[7]=bfbits(f1[3]);
        return v;
    }
    static __device__ __forceinline__ void st(void* p, size_t i, float v) {
        ((float*)p)[i] = v;
    }
};

struct Params {
    const void *lst, *lpos, *enc, *zz, *sg, *fut;
    const int* upd;
    const void *Wdec, *bdec, *Wtv, *btv, *Wih, *bih, *Whh, *bhh;
    const void *Wmu, *bmu, *Wstd, *bstd, *Wsg, *bsg;
    const int* flag;
    void* out;
};

struct __align__(16) SMem {
    bf16 pre[32][512];        // fused pre-GEMM result: [gates_zx | h0] for 32 rows
    bf16 h[32][168];          // cols 0..127 = h; 128..131 = (a0,a1,sg0,sg1); rest 0
    float sgf[NSG][32][2];
    float a0[32][2];
    float muw[4][128];
    float b4[4];
};

// flag=0 selects body<0> (fp32 I/O) — the path R2's detector resolved and
// which passed validation (absmax 7.8e-3). flag=1 (bf16 I/O) NaN'd in R5.
__global__ void k_setflag(int* __restrict__ flag) { flag[0] = 0; }

template<int BF>
__device__ __forceinline__ void body(const Params& p, SMem& s) {
    const int tid = threadIdx.x;
    const int lane = tid & 63;
    const int wav = tid >> 6;         // 0..7
    const int wn = wav & 3;
    const int wm = wav >> 2;          // 0..1
    const int c = lane & 15;
    const int quad = lane >> 4;
    const int rows0 = blockIdx.x * 32;
    const int jb = wn * 32;

    // ---------- P0: fused pre-GEMM ----------
    // wave 'wav' computes all 32 rows x cols [wav*64, wav*64+64) of
    // [W_ih[:, :1056] | W_dec_hidden] @ zx^T   (raw, biases added at consume)
    floatx4 acc2[2][4];
#pragma unroll
    for (int i = 0; i < 2; i++)
#pragma unroll
        for (int j = 0; j < 4; j++) acc2[i][j] = floatx4{0.f, 0.f, 0.f, 0.f};
    const int nb = wav * 64;
    for (int kc = 0; kc < 33; kc++) {
        const int k = kc * 32 + quad * 8;
        short8 af[2], bf8[4];
        if (kc < 32) {
            af[0] = IO<BF>::ld8(p.enc, (size_t)(rows0 + c) * MLP + k);
            af[1] = IO<BF>::ld8(p.enc, (size_t)(rows0 + 16 + c) * MLP + k);
        } else {
            af[0] = IO<BF>::ld8(p.zz, (size_t)(rows0 + c) * ZD + (k - MLP));
            af[1] = IO<BF>::ld8(p.zz, (size_t)(rows0 + 16 + c) * ZD + (k - MLP));
        }
#pragma unroll
        for (int j = 0; j < 4; j++) {
            const int n = nb + j * 16 + c;
            bf8[j] = (n < GN) ? IO<BF>::ld8(p.Wih, (size_t)n * WIH_LD + k)
                              : IO<BF>::ld8(p.Wdec, (size_t)(n - GN) * KD + k);
        }
#pragma unroll
        for (int i = 0; i < 2; i++)
#pragma unroll
            for (int j = 0; j < 4; j++)
                acc2[i][j] = __builtin_amdgcn_mfma_f32_16x16x32_bf16(
                    af[i], bf8[j], acc2[i][j], 0, 0, 0);
    }
#pragma unroll
    for (int i = 0; i < 2; i++)
#pragma unroll
        for (int j = 0; j < 4; j++)
#pragma unroll
            for (int r = 0; r < 4; r++)
                s.pre[i * 16 + quad * 4 + r][nb + j * 16 + c] = f2bf(acc2[i][j][r]);

    // ---------- prologue misc (no s.pre reads before the barrier) ----------
    for (int idx = tid; idx < 32 * 40; idx += 512)
        s.h[idx / 40][128 + (idx % 40)] = f2bf(0.0f);
    {
        int sel = tid >> 7, k = tid & 127;
        s.muw[sel][k] = (sel < 2) ? IO<BF>::ld(p.Wmu, sel * 128 + k)
                                  : IO<BF>::ld(p.Wstd, (sel - 2) * 128 + k);
    }
    if (tid < 4) s.b4[tid] = (tid < 2) ? IO<BF>::ld(p.bmu, tid) : IO<BF>::ld(p.bstd, tid - 2);
    if (tid < 32) {
        const int row = rows0 + tid;
        for (int pp = 0; pp < 2; pp++) {
            float sum = IO<BF>::ld(p.btv, pp);
            for (int f = 0; f < 6; f++)
                sum += IO<BF>::ld(p.lst, (size_t)row * 6 + f) * IO<BF>::ld(p.Wtv, pp * 6 + f);
            s.a0[tid][pp] = sum;
        }
        float px = IO<BF>::ld(p.lpos, (size_t)row * 2);
        float py = IO<BF>::ld(p.lpos, (size_t)row * 2 + 1);
        float prevx = 0.f, prevy = 0.f;
        for (int j = 0; j < NSG; j++) {
            float rx = (IO<BF>::ld(p.sg, ((size_t)row * NSG + j) * 2) - px) * 0.01f;
            float ry = (IO<BF>::ld(p.sg, ((size_t)row * NSG + j) * 2 + 1) - py) * 0.01f;
            float vx = (rx - prevx) * (1.0f / DTC), vy = (ry - prevy) * (1.0f / DTC);
            prevx = rx; prevy = ry;
            float st4[4] = {rx, ry, vx, vy};
            for (int pp = 0; pp < 2; pp++) {
                float sum = IO<BF>::ld(p.bsg, pp);
                for (int f = 0; f < 4; f++) sum += st4[f] * IO<BF>::ld(p.Wsg, pp * 4 + f);
                s.sgf[j][tid][pp] = sum;
            }
        }
    }
    int upd[4];
#pragma unroll
    for (int i = 0; i < 4; i++) upd[i] = p.upd[i];

    // W_hh fragments (step-invariant, register-resident)
    short8 Wb[2][3][4];
    short8 Wb4[2][2];
    float Wa2[2][2], Ws2[2][2], bhh2[2];
#pragma unroll
    for (int jt2 = 0; jt2 < 2; jt2++) {
#pragma unroll
        for (int g = 0; g < 3; g++) {
            const int n = g * 128 + jb + jt2 * 16 + c;
#pragma unroll
            for (int kc = 0; kc < 4; kc++)
                Wb[jt2][g][kc] = IO<BF>::ld8(p.Whh, (size_t)n * HD + kc * 32 + quad * 8);
            if (g < 2) {
                short8 v = {0, 0, 0, 0, 0, 0, 0, 0};
                if (quad == 0) {
                    v[0] = bfbits(IO<BF>::ld(p.Wih, (size_t)n * WIH_LD + KD));
                    v[1] = bfbits(IO<BF>::ld(p.Wih, (size_t)n * WIH_LD + KD + 1));
                    v[2] = bfbits(IO<BF>::ld(p.Wih, (size_t)n * WIH_LD + KD + 2));
                    v[3] = bfbits(IO<BF>::ld(p.Wih, (size_t)n * WIH_LD + KD + 3));
                }
                Wb4[jt2][g] = v;
            }
        }
        const int n2 = 256 + jb + jt2 * 16 + c;
        Wa2[jt2][0] = IO<BF>::ld(p.Wih, (size_t)n2 * WIH_LD + KD);
        Wa2[jt2][1] = IO<BF>::ld(p.Wih, (size_t)n2 * WIH_LD + KD + 1);
        Ws2[jt2][0] = IO<BF>::ld(p.Wih, (size_t)n2 * WIH_LD + KD + 2);
        Ws2[jt2][1] = IO<BF>::ld(p.Wih, (size_t)n2 * WIH_LD + KD + 3);
        bhh2[jt2] = IO<BF>::ld(p.bhh, n2);
    }

    __syncthreads();   // s.pre / misc LDS ready

    // ---------- P1: consume pre-GEMM into registers ----------
    floatx4 gzx[2][3];
#pragma unroll
    for (int jt2 = 0; jt2 < 2; jt2++) {
#pragma unroll
        for (int g = 0; g < 3; g++) {
            const int n = g * 128 + jb + jt2 * 16 + c;
            float bias = IO<BF>::ld(p.bih, n) + ((g < 2) ? IO<BF>::ld(p.bhh, n) : 0.0f);
            floatx4 v;
#pragma unroll
            for (int r = 0; r < 4; r++)
                v[r] = bf2f(s.pre[wm * 16 + quad * 4 + r][n]) + bias;
            gzx[jt2][g] = v;
        }
    }
    float hreg[2][4];
#pragma unroll
    for (int jt2 = 0; jt2 < 2; jt2++) {
        const int hcol = jb + jt2 * 16 + c;
        float bd = IO<BF>::ld(p.bdec, hcol);
#pragma unroll
        for (int r = 0; r < 4; r++) {
            const int row = wm * 16 + quad * 4 + r;
            float hv = bf2f(s.pre[row][GN + hcol]) + bd;
            hreg[jt2][r] = hv;
            s.h[row][hcol] = f2bf(hv);
        }
    }
    __syncthreads();

    // ---------- T loop ----------
    const size_t TB2 = (size_t)TT * BN * 2;
    for (int t = 0; t < TT; t++) {
        if (tid < 32) {
            const int row = rows0 + tid;
            float a0v, a1v;
            if (t == 0) { a0v = s.a0[tid][0]; a1v = s.a0[tid][1]; }
            else {
                a0v = IO<BF>::ld(p.fut, ((size_t)(t - 1) * BN + row) * 6 + 2);
                a1v = IO<BF>::ld(p.fut, ((size_t)(t - 1) * BN + row) * 6 + 3);
            }
            int jj = 0;
            for (int q = 1; q < NSG; q++) if (upd[q] <= t) jj = q;
            s.h[tid][128] = f2bf(a0v);
            s.h[tid][129] = f2bf(a1v);
            s.h[tid][130] = f2bf(s.sgf[jj][tid][0]);
            s.h[tid][131] = f2bf(s.sgf[jj][tid][1]);
        }
        __syncthreads();

        floatx4 acc[2][3];
#pragma unroll
        for (int jt2 = 0; jt2 < 2; jt2++) {
            acc[jt2][0] = gzx[jt2][0];
            acc[jt2][1] = gzx[jt2][1];
            floatx4 bb; bb[0] = bb[1] = bb[2] = bb[3] = bhh2[jt2];
            acc[jt2][2] = bb;
        }
#pragma unroll
        for (int kc = 0; kc < 4; kc++) {
            short8 am = *(const short8*)(&s.h[wm * 16 + c][kc * 32 + quad * 8]);
#pragma unroll
            for (int jt2 = 0; jt2 < 2; jt2++)
#pragma unroll
                for (int g = 0; g < 3; g++)
                    acc[jt2][g] = __builtin_amdgcn_mfma_f32_16x16x32_bf16(
                        am, Wb[jt2][g][kc], acc[jt2][g], 0, 0, 0);
        }
        {
            short8 am4 = *(const short8*)(&s.h[wm * 16 + c][128 + quad * 8]);
#pragma unroll
            for (int jt2 = 0; jt2 < 2; jt2++)
#pragma unroll
                for (int g = 0; g < 2; g++)
                    acc[jt2][g] = __builtin_amdgcn_mfma_f32_16x16x32_bf16(
                        am4, Wb4[jt2][g], acc[jt2][g], 0, 0, 0);
        }
        __syncthreads();

#pragma unroll
        for (int r = 0; r < 4; r++) {
            const int mrow = wm * 16 + quad * 4 + r;
            float a0v = bf2f(s.h[mrow][128]);
            float a1v = bf2f(s.h[mrow][129]);
            float s0v = bf2f(s.h[mrow][130]);
            float s1v = bf2f(s.h[mrow][131]);
#pragma unroll
            for (int jt2 = 0; jt2 < 2; jt2++) {
                float rr = sigm(acc[jt2][0][r]);
                float zg = sigm(acc[jt2][1][r]);
                float tn = a0v * Wa2[jt2][0] + a1v * Wa2[jt2][1]
                         + s0v * Ws2[jt2][0] + s1v * Ws2[jt2][1];
                float narg = gzx[jt2][2][r] + tn + rr * acc[jt2][2][r];
                float nn = tanh_f(narg);
                float hv = nn + zg * (hreg[jt2][r] - nn);
                hreg[jt2][r] = hv;
                s.h[mrow][jb + jt2 * 16 + c] = f2bf(hv);
            }
        }
        __syncthreads();

        if (tid < 128) {
            const int row = tid >> 2;
            const int sel = tid & 3;
            float sum = 0.0f;
#pragma unroll
            for (int k8 = 0; k8 < 16; k8++) {
                short8 hv = *(const short8*)(&s.h[row][k8 * 8]);
#pragma unroll
                for (int u = 0; u < 8; u++)
                    sum += bfraw2f((unsigned short)hv[u]) * s.muw[sel][k8 * 8 + u];
            }
            sum += s.b4[sel];
            const size_t grow = (size_t)rows0 + row;
            if (sel < 2) IO<BF>::st(p.out, ((size_t)t * BN + grow) * 2 + sel, sum);
            else IO<BF>::st(p.out, TB2 + ((size_t)t * BN + grow) * 2 + (sel - 2),
                            __expf(0.5f * sum));
        }
    }
}

__global__ __launch_bounds__(512, 2) void k_main(Params p) {
    __shared__ SMem s;
    if (*p.flag) body<1>(p, s);
    else body<0>(p, s);
}

extern "C" void kernel_launch(void* const* d_in, const int* in_sizes, int n_in,
                              void* d_out, int out_size, void* d_ws, size_t ws_size,
                              hipStream_t stream) {
    Params p;
    p.lst  = d_in[0];
    p.lpos = d_in[1];
    p.enc  = d_in[2];
    p.zz   = d_in[3];
    p.sg   = d_in[4];
    p.fut  = d_in[5];
    p.upd  = (const int*)d_in[6];
    p.Wdec = d_in[7];
    p.bdec = d_in[8];
    p.Wtv  = d_in[9];
    p.btv  = d_in[10];
    p.Wih  = d_in[11];
    p.bih  = d_in[12];
    p.Whh  = d_in[13];
    p.bhh  = d_in[14];
    p.Wmu  = d_in[15];
    p.bmu  = d_in[16];
    p.Wstd = d_in[17];
    p.bstd = d_in[18];
    p.Wsg  = d_in[19];
    p.bsg  = d_in[20];
    p.flag = (const int*)d_ws;
    p.out  = d_out;

    k_setflag<<<1, 1, 0, stream>>>((int*)d_ws);
    k_main<<<512, 512, 0, stream>>>(p);
}

// Round 7
// 292.236 us; speedup vs baseline: 1.2787x; 1.2717x over previous
//
#include <hip/hip_runtime.h>
#include <hip/hip_bf16.h>

#define BN 16384
#define TT 12
#define MLP 1024
#define ZD 32
#define HD 128
#define KD 1056          // MLP+ZD
#define GN 384           // 3*H
#define WIH_LD 1060      // MLP+ZD+2*NPRED
#define NSG 4
#define DTC 1.6f
#define PLD 512          // P leading dim: [gates_zx(384) | h0(128)]
#define SLD 40           // LDS tile row stride (bf16 elems): 80B -> <=2-way banks

typedef __attribute__((ext_vector_type(8))) short short8;
typedef __attribute__((ext_vector_type(4))) short short4_t;
typedef __attribute__((ext_vector_type(4))) float floatx4;
typedef __hip_bfloat16 bf16;

__device__ __forceinline__ float bf2f(bf16 v) { return __bfloat162float(v); }
__device__ __forceinline__ bf16 f2bf(float v) { return __float2bfloat16(v); }
__device__ __forceinline__ short bfbits(float x) {
    bf16 t = __float2bfloat16(x);
    return __builtin_bit_cast(short, t);
}
__device__ __forceinline__ float bfraw2f(unsigned short u) {
    return __uint_as_float(((unsigned int)u) << 16);
}
__device__ __forceinline__ float sigm(float x) { return __fdividef(1.0f, 1.0f + __expf(-x)); }
__device__ __forceinline__ float tanh_f(float x) {
    float t = __expf(-2.0f * x);
    return __fdividef(2.0f, 1.0f + t) - 1.0f;
}
// pack 8 fp32 -> bf16 fragment
__device__ __forceinline__ short8 pack8(floatx4 a, floatx4 b) {
    short8 v;
    v[0]=bfbits(a[0]); v[1]=bfbits(a[1]); v[2]=bfbits(a[2]); v[3]=bfbits(a[3]);
    v[4]=bfbits(b[0]); v[5]=bfbits(b[1]); v[6]=bfbits(b[2]); v[7]=bfbits(b[3]);
    return v;
}
// load 8 consecutive fp32 (16B-aligned) as bf16 fragment
__device__ __forceinline__ short8 ld8f(const float* q) {
    return pack8(*(const floatx4*)q, *(const floatx4*)(q + 4));
}

struct GP {
    const float *lst, *lpos, *enc, *zz, *sg, *fut;
    const int* upd;
    const float *Wdec, *bdec, *Wtv, *btv, *Wih, *bih, *Whh, *bhh;
    const float *Wmu, *bmu, *Wstd, *bstd, *Wsg, *bsg;
    const bf16* P;        // null in fused path
    float* out;
};

// ---------------------------------------------------------------------------
// k_gemm: P[B,512] = zx @ [W_ih[:, :1056] | W_dec_hidden]^T  (raw, no bias)
// Tile 128x128, grid (128,4), 512 thr (8 waves, 2x4). LDS-staged, bf16 MFMA.
// ---------------------------------------------------------------------------
__global__ __launch_bounds__(512, 2) void k_gemm(
    const float* __restrict__ enc, const float* __restrict__ zz,
    const float* __restrict__ Wih, const float* __restrict__ Wdec,
    bf16* __restrict__ P)
{
    __shared__ __align__(16) bf16 sA[128 * SLD];
    __shared__ __align__(16) bf16 sB[128 * SLD];
    const int tid = threadIdx.x;
    const int lane = tid & 63;
    const int wav = tid >> 6;
    const int wm2 = wav >> 2;         // 0..1 (M 64-halves)
    const int wn2 = wav & 3;          // 0..3 (N 32-quarters)
    const int c = lane & 15;
    const int quad = lane >> 4;
    const int m0 = blockIdx.x * 128;
    const int n0 = blockIdx.y * 128;

    floatx4 acc[4][2];
#pragma unroll
    for (int i = 0; i < 4; i++)
#pragma unroll
        for (int j = 0; j < 2; j++) acc[i][j] = floatx4{0.f, 0.f, 0.f, 0.f};

    const int srow = tid >> 2;        // 0..127
    const int scq = (tid & 3) * 8;    // 0/8/16/24

    for (int kc = 0; kc < 33; kc++) {
        const int k = kc * 32;
        // stage A tile: rows m0..m0+128, cols k..k+32
        {
            const float* src = (kc < 32)
                ? enc + (size_t)(m0 + srow) * MLP + k + scq
                : zz + (size_t)(m0 + srow) * ZD + scq;
            short8 v = ld8f(src);
            // stage B tile: weight rows n0..n0+128, cols k..k+32
            const int nn = n0 + srow;
            const float* srcb = (nn < GN)
                ? Wih + (size_t)nn * WIH_LD + k + scq
                : Wdec + (size_t)(nn - GN) * KD + k + scq;
            short8 w = ld8f(srcb);
            *(short8*)&sA[srow * SLD + scq] = v;
            *(short8*)&sB[srow * SLD + scq] = w;
        }
        __syncthreads();
        short8 a[4], b[2];
#pragma unroll
        for (int i = 0; i < 4; i++)
            a[i] = *(const short8*)&sA[(wm2 * 64 + i * 16 + c) * SLD + quad * 8];
#pragma unroll
        for (int j = 0; j < 2; j++)
            b[j] = *(const short8*)&sB[(wn2 * 32 + j * 16 + c) * SLD + quad * 8];
#pragma unroll
        for (int i = 0; i < 4; i++)
#pragma unroll
            for (int j = 0; j < 2; j++)
                acc[i][j] = __builtin_amdgcn_mfma_f32_16x16x32_bf16(
                    a[i], b[j], acc[i][j], 0, 0, 0);
        __syncthreads();
    }
#pragma unroll
    for (int i = 0; i < 4; i++)
#pragma unroll
        for (int j = 0; j < 2; j++)
#pragma unroll
            for (int r = 0; r < 4; r++)
                P[(size_t)(m0 + wm2 * 64 + i * 16 + quad * 4 + r) * PLD
                  + n0 + wn2 * 32 + j * 16 + c] = f2bf(acc[i][j][r]);
}

// ---------------------------------------------------------------------------
// GRU kernel (R6-proven body). FUSED=1: in-block pre-GEMM (ws too small).
// FUSED=0: read P from ws. 512 blocks x 512 threads, 32 batch rows/block.
// ---------------------------------------------------------------------------
template<int FUSED> struct SMem {
    static constexpr int PRE_N = FUSED ? 32 * 512 : 16;
    bf16 pre[PRE_N];
    bf16 h[32][168];          // cols 0..127 = h; 128..131 = ext; 132..159 = 0
    float sgf[NSG][32][2];
    float a0[32][2];
    float muw[4][128];
    float b4[4];
};

template<int FUSED>
__global__ __launch_bounds__(512, 2) void k_gru(GP p) {
    __shared__ __align__(16) SMem<FUSED> s;
    const int tid = threadIdx.x;
    const int lane = tid & 63;
    const int wav = tid >> 6;         // 0..7
    const int wn = wav & 3;
    const int wm = wav >> 2;          // 0..1
    const int c = lane & 15;
    const int quad = lane >> 4;
    const int rows0 = blockIdx.x * 32;
    const int jb = wn * 32;

    // ---------- P0 (fused only): in-block pre-GEMM ----------
    if constexpr (FUSED) {
        floatx4 acc2[2][4];
#pragma unroll
        for (int i = 0; i < 2; i++)
#pragma unroll
            for (int j = 0; j < 4; j++) acc2[i][j] = floatx4{0.f, 0.f, 0.f, 0.f};
        const int nb = wav * 64;
        for (int kc = 0; kc < 33; kc++) {
            const int k = kc * 32 + quad * 8;
            short8 af[2], bf8[4];
            if (kc < 32) {
                af[0] = ld8f(p.enc + (size_t)(rows0 + c) * MLP + k);
                af[1] = ld8f(p.enc + (size_t)(rows0 + 16 + c) * MLP + k);
            } else {
                af[0] = ld8f(p.zz + (size_t)(rows0 + c) * ZD + (k - MLP));
                af[1] = ld8f(p.zz + (size_t)(rows0 + 16 + c) * ZD + (k - MLP));
            }
#pragma unroll
            for (int j = 0; j < 4; j++) {
                const int n = nb + j * 16 + c;
                bf8[j] = (n < GN) ? ld8f(p.Wih + (size_t)n * WIH_LD + k)
                                  : ld8f(p.Wdec + (size_t)(n - GN) * KD + k);
            }
#pragma unroll
            for (int i = 0; i < 2; i++)
#pragma unroll
                for (int j = 0; j < 4; j++)
                    acc2[i][j] = __builtin_amdgcn_mfma_f32_16x16x32_bf16(
                        af[i], bf8[j], acc2[i][j], 0, 0, 0);
        }
#pragma unroll
        for (int i = 0; i < 2; i++)
#pragma unroll
            for (int j = 0; j < 4; j++)
#pragma unroll
                for (int r = 0; r < 4; r++)
                    s.pre[(i * 16 + quad * 4 + r) * 512 + nb + j * 16 + c] =
                        f2bf(acc2[i][j][r]);
    }

    // ---------- prologue misc ----------
    for (int idx = tid; idx < 32 * 40; idx += 512)
        s.h[idx / 40][128 + (idx % 40)] = f2bf(0.0f);
    {
        int sel = tid >> 7, k = tid & 127;
        s.muw[sel][k] = (sel < 2) ? p.Wmu[sel * 128 + k] : p.Wstd[(sel - 2) * 128 + k];
    }
    if (tid < 4) s.b4[tid] = (tid < 2) ? p.bmu[tid] : p.bstd[tid - 2];
    if (tid < 32) {
        const int row = rows0 + tid;
        for (int pp = 0; pp < 2; pp++) {
            float sum = p.btv[pp];
            for (int f = 0; f < 6; f++)
                sum += p.lst[(size_t)row * 6 + f] * p.Wtv[pp * 6 + f];
            s.a0[tid][pp] = sum;
        }
        float px = p.lpos[(size_t)row * 2];
        float py = p.lpos[(size_t)row * 2 + 1];
        float prevx = 0.f, prevy = 0.f;
        for (int j = 0; j < NSG; j++) {
            float rx = (p.sg[((size_t)row * NSG + j) * 2] - px) * 0.01f;
            float ry = (p.sg[((size_t)row * NSG + j) * 2 + 1] - py) * 0.01f;
            float vx = (rx - prevx) * (1.0f / DTC), vy = (ry - prevy) * (1.0f / DTC);
            prevx = rx; prevy = ry;
            float st4[4] = {rx, ry, vx, vy};
            for (int pp = 0; pp < 2; pp++) {
                float sum = p.bsg[pp];
                for (int f = 0; f < 4; f++) sum += st4[f] * p.Wsg[pp * 4 + f];
                s.sgf[j][tid][pp] = sum;
            }
        }
    }
    int upd[4];
#pragma unroll
    for (int i = 0; i < 4; i++) upd[i] = p.upd[i];

    // W_hh fragments (step-invariant, register-resident)
    short8 Wb[2][3][4];
    short8 Wb4[2][2];
    float Wa2[2][2], Ws2[2][2], bhh2[2];
#pragma unroll
    for (int jt2 = 0; jt2 < 2; jt2++) {
#pragma unroll
        for (int g = 0; g < 3; g++) {
            const int n = g * 128 + jb + jt2 * 16 + c;
#pragma unroll
            for (int kc = 0; kc < 4; kc++)
                Wb[jt2][g][kc] = ld8f(p.Whh + (size_t)n * HD + kc * 32 + quad * 8);
            if (g < 2) {
                short8 v = {0, 0, 0, 0, 0, 0, 0, 0};
                if (quad == 0) {
                    const float* q = p.Wih + (size_t)n * WIH_LD + KD;
                    v[0] = bfbits(q[0]); v[1] = bfbits(q[1]);
                    v[2] = bfbits(q[2]); v[3] = bfbits(q[3]);
                }
                Wb4[jt2][g] = v;
            }
        }
        const int n2 = 256 + jb + jt2 * 16 + c;
        const float* q2 = p.Wih + (size_t)n2 * WIH_LD + KD;
        Wa2[jt2][0] = q2[0]; Wa2[jt2][1] = q2[1];
        Ws2[jt2][0] = q2[2]; Ws2[jt2][1] = q2[3];
        bhh2[jt2] = p.bhh[n2];
    }

    __syncthreads();   // s.pre (if fused) / misc LDS ready

    // ---------- P1: consume pre-GEMM into registers ----------
    floatx4 gzx[2][3];
#pragma unroll
    for (int jt2 = 0; jt2 < 2; jt2++) {
#pragma unroll
        for (int g = 0; g < 3; g++) {
            const int n = g * 128 + jb + jt2 * 16 + c;
            float bias = p.bih[n] + ((g < 2) ? p.bhh[n] : 0.0f);
            floatx4 v;
#pragma unroll
            for (int r = 0; r < 4; r++) {
                const int mrow = wm * 16 + quad * 4 + r;
                float raw;
                if constexpr (FUSED) raw = bf2f(s.pre[mrow * 512 + n]);
                else raw = bf2f(p.P[(size_t)(rows0 + mrow) * PLD + n]);
                v[r] = raw + bias;
            }
            gzx[jt2][g] = v;
        }
    }
    float hreg[2][4];
#pragma unroll
    for (int jt2 = 0; jt2 < 2; jt2++) {
        const int hcol = jb + jt2 * 16 + c;
        float bd = p.bdec[hcol];
#pragma unroll
        for (int r = 0; r < 4; r++) {
            const int mrow = wm * 16 + quad * 4 + r;
            float raw;
            if constexpr (FUSED) raw = bf2f(s.pre[mrow * 512 + GN + hcol]);
            else raw = bf2f(p.P[(size_t)(rows0 + mrow) * PLD + GN + hcol]);
            float hv = raw + bd;
            hreg[jt2][r] = hv;
            s.h[mrow][hcol] = f2bf(hv);
        }
    }
    __syncthreads();

    // ---------- T loop (R6-proven: 3 barriers/step) ----------
    const size_t TB2 = (size_t)TT * BN * 2;
    for (int t = 0; t < TT; t++) {
        if (tid < 32) {
            const int row = rows0 + tid;
            float a0v, a1v;
            if (t == 0) { a0v = s.a0[tid][0]; a1v = s.a0[tid][1]; }
            else {
                a0v = p.fut[((size_t)(t - 1) * BN + row) * 6 + 2];
                a1v = p.fut[((size_t)(t - 1) * BN + row) * 6 + 3];
            }
            int jj = 0;
            for (int q = 1; q < NSG; q++) if (upd[q] <= t) jj = q;
            s.h[tid][128] = f2bf(a0v);
            s.h[tid][129] = f2bf(a1v);
            s.h[tid][130] = f2bf(s.sgf[jj][tid][0]);
            s.h[tid][131] = f2bf(s.sgf[jj][tid][1]);
        }
        __syncthreads();

        floatx4 acc[2][3];
#pragma unroll
        for (int jt2 = 0; jt2 < 2; jt2++) {
            acc[jt2][0] = gzx[jt2][0];
            acc[jt2][1] = gzx[jt2][1];
            floatx4 bb; bb[0] = bb[1] = bb[2] = bb[3] = bhh2[jt2];
            acc[jt2][2] = bb;
        }
#pragma unroll
        for (int kc = 0; kc < 4; kc++) {
            short8 am = *(const short8*)(&s.h[wm * 16 + c][kc * 32 + quad * 8]);
#pragma unroll
            for (int jt2 = 0; jt2 < 2; jt2++)
#pragma unroll
                for (int g = 0; g < 3; g++)
                    acc[jt2][g] = __builtin_amdgcn_mfma_f32_16x16x32_bf16(
                        am, Wb[jt2][g][kc], acc[jt2][g], 0, 0, 0);
        }
        {
            short8 am4 = *(const short8*)(&s.h[wm * 16 + c][128 + quad * 8]);
#pragma unroll
            for (int jt2 = 0; jt2 < 2; jt2++)
#pragma unroll
                for (int g = 0; g < 2; g++)
                    acc[jt2][g] = __builtin_amdgcn_mfma_f32_16x16x32_bf16(
                        am4, Wb4[jt2][g], acc[jt2][g], 0, 0, 0);
        }
        __syncthreads();

#pragma unroll
        for (int r = 0; r < 4; r++) {
            const int mrow = wm * 16 + quad * 4 + r;
            float a0v = bf2f(s.h[mrow][128]);
            float a1v = bf2f(s.h[mrow][129]);
            float s0v = bf2f(s.h[mrow][130]);
            float s1v = bf2f(s.h[mrow][131]);
#pragma unroll
            for (int jt2 = 0; jt2 < 2; jt2++) {
                float rr = sigm(acc[jt2][0][r]);
                float zg = sigm(acc[jt2][1][r]);
                float tn = a0v * Wa2[jt2][0] + a1v * Wa2[jt2][1]
                         + s0v * Ws2[jt2][0] + s1v * Ws2[jt2][1];
                float narg = gzx[jt2][2][r] + tn + rr * acc[jt2][2][r];
                float nn = tanh_f(narg);
                float hv = nn + zg * (hreg[jt2][r] - nn);
                hreg[jt2][r] = hv;
                s.h[mrow][jb + jt2 * 16 + c] = f2bf(hv);
            }
        }
        __syncthreads();

        if (tid < 128) {
            const int row = tid >> 2;
            const int sel = tid & 3;
            float sum = 0.0f;
#pragma unroll
            for (int k8 = 0; k8 < 16; k8++) {
                short8 hv = *(const short8*)(&s.h[row][k8 * 8]);
#pragma unroll
                for (int u = 0; u < 8; u++)
                    sum += bfraw2f((unsigned short)hv[u]) * s.muw[sel][k8 * 8 + u];
            }
            sum += s.b4[sel];
            const size_t grow = (size_t)rows0 + row;
            if (sel < 2) p.out[((size_t)t * BN + grow) * 2 + sel] = sum;
            else p.out[TB2 + ((size_t)t * BN + grow) * 2 + (sel - 2)] =
                     __expf(0.5f * sum);
        }
    }
}

extern "C" void kernel_launch(void* const* d_in, const int* in_sizes, int n_in,
                              void* d_out, int out_size, void* d_ws, size_t ws_size,
                              hipStream_t stream) {
    GP p;
    p.lst  = (const float*)d_in[0];
    p.lpos = (const float*)d_in[1];
    p.enc  = (const float*)d_in[2];
    p.zz   = (const float*)d_in[3];
    p.sg   = (const float*)d_in[4];
    p.fut  = (const float*)d_in[5];
    p.upd  = (const int*)d_in[6];
    p.Wdec = (const float*)d_in[7];
    p.bdec = (const float*)d_in[8];
    p.Wtv  = (const float*)d_in[9];
    p.btv  = (const float*)d_in[10];
    p.Wih  = (const float*)d_in[11];
    p.bih  = (const float*)d_in[12];
    p.Whh  = (const float*)d_in[13];
    p.bhh  = (const float*)d_in[14];
    p.Wmu  = (const float*)d_in[15];
    p.bmu  = (const float*)d_in[16];
    p.Wstd = (const float*)d_in[17];
    p.bstd = (const float*)d_in[18];
    p.Wsg  = (const float*)d_in[19];
    p.bsg  = (const float*)d_in[20];
    p.out  = (float*)d_out;
    p.P    = nullptr;

    const size_t needP = (size_t)BN * PLD * sizeof(bf16);   // 16.78 MB
    if (ws_size >= needP) {
        bf16* P = (bf16*)d_ws;
        p.P = P;
        k_gemm<<<dim3(128, 4), 512, 0, stream>>>(p.enc, p.zz, p.Wih, p.Wdec, P);
        k_gru<0><<<512, 512, 0, stream>>>(p);
    } else {
        k_gru<1><<<512, 512, 0, stream>>>(p);
    }
}

// Round 8
// 262.913 us; speedup vs baseline: 1.4213x; 1.1115x over previous
//
#include <hip/hip_runtime.h>
#include <hip/hip_bf16.h>

#define BN 16384
#define TT 12
#define MLP 1024
#define ZD 32
#define HD 128
#define KD 1056          // MLP+ZD
#define GN 384           // 3*H
#define WIH_LD 1060      // MLP+ZD+2*NPRED
#define NSG 4
#define DTC 1.6f
#define PLD 512          // P leading dim: [gates_zx(384) | h0(128)]
#define SLD 40           // GEMM LDS tile row stride (bf16): 80B -> <=2-way banks

typedef __attribute__((ext_vector_type(8))) short short8;
typedef __attribute__((ext_vector_type(4))) short short4_t;
typedef __attribute__((ext_vector_type(4))) float floatx4;
typedef __hip_bfloat16 bf16;

__device__ __forceinline__ float bf2f(bf16 v) { return __bfloat162float(v); }
__device__ __forceinline__ bf16 f2bf(float v) { return __float2bfloat16(v); }
__device__ __forceinline__ short bfbits(float x) {
    bf16 t = __float2bfloat16(x);
    return __builtin_bit_cast(short, t);
}
__device__ __forceinline__ float bfraw2f(unsigned short u) {
    return __uint_as_float(((unsigned int)u) << 16);
}
// rcp-based gates: saves div sequence; |err| ~1ulp of rcp, fine vs 3.4e-2 thr
__device__ __forceinline__ float sigm(float x) {
    return __builtin_amdgcn_rcpf(1.0f + __expf(-x));
}
__device__ __forceinline__ float tanh_f(float x) {
    return 1.0f - 2.0f * __builtin_amdgcn_rcpf(1.0f + __expf(2.0f * x));
}
__device__ __forceinline__ short8 pack8(floatx4 a, floatx4 b) {
    short8 v;
    v[0]=bfbits(a[0]); v[1]=bfbits(a[1]); v[2]=bfbits(a[2]); v[3]=bfbits(a[3]);
    v[4]=bfbits(b[0]); v[5]=bfbits(b[1]); v[6]=bfbits(b[2]); v[7]=bfbits(b[3]);
    return v;
}
__device__ __forceinline__ short8 ld8f(const float* q) {
    return pack8(*(const floatx4*)q, *(const floatx4*)(q + 4));
}
// barrier that waits LDS ops only — leaves global loads/stores in flight
__device__ __forceinline__ void barrier_lgkm() {
    asm volatile("s_waitcnt lgkmcnt(0)\n\ts_barrier" ::: "memory");
}

struct GP {
    const float *lst, *lpos, *enc, *zz, *sg, *fut;
    const int* upd;
    const float *Wdec, *bdec, *Wtv, *btv, *Wih, *bih, *Whh, *bhh;
    const float *Wmu, *bmu, *Wstd, *bstd, *Wsg, *bsg;
    const bf16* P;        // null in fused path
    float* out;
};

// ---------------------------------------------------------------------------
// k_gemm: P[B,512] = zx @ [W_ih[:, :1056] | W_dec_hidden]^T  (raw, no bias)
// Tile 128x128, grid (128,4). Double-buffered LDS, 2-deep register prefetch,
// one lgkm-only barrier per kc (global loads fly across barriers).
// ---------------------------------------------------------------------------
__global__ __launch_bounds__(512, 4) void k_gemm(
    const float* __restrict__ enc, const float* __restrict__ zz,
    const float* __restrict__ Wih, const float* __restrict__ Wdec,
    bf16* __restrict__ P)
{
    __shared__ __align__(16) bf16 sA[2][128 * SLD];
    __shared__ __align__(16) bf16 sB[2][128 * SLD];
    const int tid = threadIdx.x;
    const int lane = tid & 63;
    const int wav = tid >> 6;
    const int wm2 = wav >> 2;         // 0..1
    const int wn2 = wav & 3;          // 0..3
    const int c = lane & 15;
    const int quad = lane >> 4;
    const int m0 = blockIdx.x * 128;
    const int n0 = blockIdx.y * 128;

    const int srow = tid >> 2;        // 0..127
    const int scq = (tid & 3) * 8;    // 0/8/16/24
    const int nn = n0 + srow;
    const float* arow = enc + (size_t)(m0 + srow) * MLP + scq;
    const float* zrow = zz + (size_t)(m0 + srow) * ZD + scq;
    const float* brow = (nn < GN) ? Wih + (size_t)nn * WIH_LD + scq
                                  : Wdec + (size_t)(nn - GN) * KD + scq;

    floatx4 pa[2][2], pb[2][2];
    // preload kc=0 (slot 0) and kc=1 (slot 1)
#pragma unroll
    for (int s0 = 0; s0 < 2; s0++) {
        const float* qa = arow + s0 * 32;
        const float* qb = brow + s0 * 32;
        pa[s0][0] = *(const floatx4*)qa; pa[s0][1] = *(const floatx4*)(qa + 4);
        pb[s0][0] = *(const floatx4*)qb; pb[s0][1] = *(const floatx4*)(qb + 4);
    }

    floatx4 acc[4][2];
#pragma unroll
    for (int i = 0; i < 4; i++)
#pragma unroll
        for (int j = 0; j < 2; j++) acc[i][j] = floatx4{0.f, 0.f, 0.f, 0.f};

    for (int kc = 0; kc < 33; kc++) {
        const int sl = kc & 1;
        *(short8*)&sA[sl][srow * SLD + scq] = pack8(pa[sl][0], pa[sl][1]);
        *(short8*)&sB[sl][srow * SLD + scq] = pack8(pb[sl][0], pb[sl][1]);
        if (kc + 2 < 33) {
            const int k2 = (kc + 2) * 32;
            const float* qa = (kc + 2 < 32) ? arow + k2 : zrow;
            const float* qb = brow + k2;
            pa[sl][0] = *(const floatx4*)qa; pa[sl][1] = *(const floatx4*)(qa + 4);
            pb[sl][0] = *(const floatx4*)qb; pb[sl][1] = *(const floatx4*)(qb + 4);
        }
        barrier_lgkm();
        short8 a[4], b[2];
#pragma unroll
        for (int i = 0; i < 4; i++)
            a[i] = *(const short8*)&sA[sl][(wm2 * 64 + i * 16 + c) * SLD + quad * 8];
#pragma unroll
        for (int j = 0; j < 2; j++)
            b[j] = *(const short8*)&sB[sl][(wn2 * 32 + j * 16 + c) * SLD + quad * 8];
#pragma unroll
        for (int i = 0; i < 4; i++)
#pragma unroll
            for (int j = 0; j < 2; j++)
                acc[i][j] = __builtin_amdgcn_mfma_f32_16x16x32_bf16(
                    a[i], b[j], acc[i][j], 0, 0, 0);
        // no trailing barrier: next iter writes the other LDS slot; all waves'
        // slot-sl reads are lgkm-complete before anyone passes the next barrier
    }
#pragma unroll
    for (int i = 0; i < 4; i++)
#pragma unroll
        for (int j = 0; j < 2; j++)
#pragma unroll
            for (int r = 0; r < 4; r++)
                P[(size_t)(m0 + wm2 * 64 + i * 16 + quad * 4 + r) * PLD
                  + n0 + wn2 * 32 + j * 16 + c] = f2bf(acc[i][j][r]);
}

// ---------------------------------------------------------------------------
// GRU kernel. FUSED=1: in-block pre-GEMM (ws too small). FUSED=0: read P.
// 512 blocks x 512 threads, 32 rows/block. 1 barrier/step (h double-buffer),
// ext staged for all steps, heads(t-1) overlapped with MFMA(t).
// ---------------------------------------------------------------------------
template<int FUSED> struct SMem {
    static constexpr int PRE_N = FUSED ? 32 * 512 : 16;
    bf16 pre[PRE_N];
    bf16 h[2][32][136];       // 272B rows: 2-way banks (free) for b128 reads
    bf16 ext[TT][32][4];      // per-step (a0,a1,sg0,sg1)
    float sgf[NSG][32][2];
    float a0[32][2];
    float muw[4][132];        // +4 pad: kills 4-way same-bank head reads
    float b4[4];
};

template<int FUSED>
__device__ __forceinline__ void heads_out(const SMem<FUSED>& s, const GP& p,
                                          int rows0, int t, int buf, int tid) {
    const int row = tid >> 2;
    const int sel = tid & 3;
    float sum = 0.0f;
#pragma unroll
    for (int k8 = 0; k8 < 16; k8++) {
        short8 hv = *(const short8*)(&s.h[buf][row][k8 * 8]);
#pragma unroll
        for (int u = 0; u < 8; u++)
            sum += bfraw2f((unsigned short)hv[u]) * s.muw[sel][k8 * 8 + u];
    }
    sum += s.b4[sel];
    const size_t TB2 = (size_t)TT * BN * 2;
    const size_t grow = (size_t)rows0 + row;
    if (sel < 2) p.out[((size_t)t * BN + grow) * 2 + sel] = sum;
    else p.out[TB2 + ((size_t)t * BN + grow) * 2 + (sel - 2)] = __expf(0.5f * sum);
}

template<int FUSED>
__global__ __launch_bounds__(512, 2) void k_gru(GP p) {
    __shared__ __align__(16) SMem<FUSED> s;
    const int tid = threadIdx.x;
    const int lane = tid & 63;
    const int wav = tid >> 6;         // 0..7
    const int wn = wav & 3;
    const int wm = wav >> 2;          // 0..1
    const int c = lane & 15;
    const int quad = lane >> 4;
    const int rows0 = blockIdx.x * 32;
    const int jb = wn * 32;

    // ---------- P0 (fused only): in-block pre-GEMM ----------
    if constexpr (FUSED) {
        floatx4 acc2[2][4];
#pragma unroll
        for (int i = 0; i < 2; i++)
#pragma unroll
            for (int j = 0; j < 4; j++) acc2[i][j] = floatx4{0.f, 0.f, 0.f, 0.f};
        const int nb = wav * 64;
        for (int kc = 0; kc < 33; kc++) {
            const int k = kc * 32 + quad * 8;
            short8 af[2], bf8[4];
            if (kc < 32) {
                af[0] = ld8f(p.enc + (size_t)(rows0 + c) * MLP + k);
                af[1] = ld8f(p.enc + (size_t)(rows0 + 16 + c) * MLP + k);
            } else {
                af[0] = ld8f(p.zz + (size_t)(rows0 + c) * ZD + (k - MLP));
                af[1] = ld8f(p.zz + (size_t)(rows0 + 16 + c) * ZD + (k - MLP));
            }
#pragma unroll
            for (int j = 0; j < 4; j++) {
                const int n = nb + j * 16 + c;
                bf8[j] = (n < GN) ? ld8f(p.Wih + (size_t)n * WIH_LD + k)
                                  : ld8f(p.Wdec + (size_t)(n - GN) * KD + k);
            }
#pragma unroll
            for (int i = 0; i < 2; i++)
#pragma unroll
                for (int j = 0; j < 4; j++)
                    acc2[i][j] = __builtin_amdgcn_mfma_f32_16x16x32_bf16(
                        af[i], bf8[j], acc2[i][j], 0, 0, 0);
        }
#pragma unroll
        for (int i = 0; i < 2; i++)
#pragma unroll
            for (int j = 0; j < 4; j++)
#pragma unroll
                for (int r = 0; r < 4; r++)
                    s.pre[(i * 16 + quad * 4 + r) * 512 + nb + j * 16 + c] =
                        f2bf(acc2[i][j][r]);
    }

    // ---------- prologue misc ----------
    {
        int sel = tid >> 7, k = tid & 127;
        s.muw[sel][k] = (sel < 2) ? p.Wmu[sel * 128 + k] : p.Wstd[(sel - 2) * 128 + k];
    }
    if (tid < 4) s.b4[tid] = (tid < 2) ? p.bmu[tid] : p.bstd[tid - 2];
    if (tid < 32) {
        const int row = rows0 + tid;
        for (int pp = 0; pp < 2; pp++) {
            float sum = p.btv[pp];
            for (int f = 0; f < 6; f++)
                sum += p.lst[(size_t)row * 6 + f] * p.Wtv[pp * 6 + f];
            s.a0[tid][pp] = sum;
        }
        float px = p.lpos[(size_t)row * 2];
        float py = p.lpos[(size_t)row * 2 + 1];
        float prevx = 0.f, prevy = 0.f;
        for (int j = 0; j < NSG; j++) {
            float rx = (p.sg[((size_t)row * NSG + j) * 2] - px) * 0.01f;
            float ry = (p.sg[((size_t)row * NSG + j) * 2 + 1] - py) * 0.01f;
            float vx = (rx - prevx) * (1.0f / DTC), vy = (ry - prevy) * (1.0f / DTC);
            prevx = rx; prevy = ry;
            float st4[4] = {rx, ry, vx, vy};
            for (int pp = 0; pp < 2; pp++) {
                float sum = p.bsg[pp];
                for (int f = 0; f < 4; f++) sum += st4[f] * p.Wsg[pp * 4 + f];
                s.sgf[j][tid][pp] = sum;
            }
        }
    }
    int upd[4];
#pragma unroll
    for (int i = 0; i < 4; i++) upd[i] = p.upd[i];

    // W_hh fragments (step-invariant, register-resident)
    short8 Wb[2][3][4];
    short8 Wb4[2][2];
    float Wa2[2][2], Ws2[2][2], bhh2[2];
#pragma unroll
    for (int jt2 = 0; jt2 < 2; jt2++) {
#pragma unroll
        for (int g = 0; g < 3; g++) {
            const int n = g * 128 + jb + jt2 * 16 + c;
#pragma unroll
            for (int kc = 0; kc < 4; kc++)
                Wb[jt2][g][kc] = ld8f(p.Whh + (size_t)n * HD + kc * 32 + quad * 8);
            if (g < 2) {
                short8 v = {0, 0, 0, 0, 0, 0, 0, 0};
                if (quad == 0) {
                    const float* q = p.Wih + (size_t)n * WIH_LD + KD;
                    v[0] = bfbits(q[0]); v[1] = bfbits(q[1]);
                    v[2] = bfbits(q[2]); v[3] = bfbits(q[3]);
                }
                Wb4[jt2][g] = v;
            }
        }
        const int n2 = 256 + jb + jt2 * 16 + c;
        const float* q2 = p.Wih + (size_t)n2 * WIH_LD + KD;
        Wa2[jt2][0] = q2[0]; Wa2[jt2][1] = q2[1];
        Ws2[jt2][0] = q2[2]; Ws2[jt2][1] = q2[3];
        bhh2[jt2] = p.bhh[n2];
    }

    __syncthreads();   // s.pre (if fused) + sgf/a0/muw ready

    // ---------- P1: consume pre-GEMM; h0 -> buf 1; stage all ext ----------
    floatx4 gzx[2][3];
#pragma unroll
    for (int jt2 = 0; jt2 < 2; jt2++) {
#pragma unroll
        for (int g = 0; g < 3; g++) {
            const int n = g * 128 + jb + jt2 * 16 + c;
            float bias = p.bih[n] + ((g < 2) ? p.bhh[n] : 0.0f);
            floatx4 v;
#pragma unroll
            for (int r = 0; r < 4; r++) {
                const int mrow = wm * 16 + quad * 4 + r;
                float raw;
                if constexpr (FUSED) raw = bf2f(s.pre[mrow * 512 + n]);
                else raw = bf2f(p.P[(size_t)(rows0 + mrow) * PLD + n]);
                v[r] = raw + bias;
            }
            gzx[jt2][g] = v;
        }
    }
    float hreg[2][4];
#pragma unroll
    for (int jt2 = 0; jt2 < 2; jt2++) {
        const int hcol = jb + jt2 * 16 + c;
        float bd = p.bdec[hcol];
#pragma unroll
        for (int r = 0; r < 4; r++) {
            const int mrow = wm * 16 + quad * 4 + r;
            float raw;
            if constexpr (FUSED) raw = bf2f(s.pre[mrow * 512 + GN + hcol]);
            else raw = bf2f(p.P[(size_t)(rows0 + mrow) * PLD + GN + hcol]);
            float hv = raw + bd;
            hreg[jt2][r] = hv;
            s.h[1][mrow][hcol] = f2bf(hv);
        }
    }
    if (tid < TT * 32) {
        const int t = tid >> 5, row = tid & 31;
        float a0v, a1v;
        if (t == 0) { a0v = s.a0[row][0]; a1v = s.a0[row][1]; }
        else {
            const float* fp = p.fut + ((size_t)(t - 1) * BN + rows0 + row) * 6 + 2;
            a0v = fp[0]; a1v = fp[1];
        }
        int jj = 0;
#pragma unroll
        for (int q = 1; q < NSG; q++) if (upd[q] <= t) jj = q;
        s.ext[t][row][0] = f2bf(a0v);
        s.ext[t][row][1] = f2bf(a1v);
        s.ext[t][row][2] = f2bf(s.sgf[jj][row][0]);
        s.ext[t][row][3] = f2bf(s.sgf[jj][row][1]);
    }
    __syncthreads();

    // ---------- T loop: 1 lgkm-barrier per step ----------
    for (int t = 0; t < TT; t++) {
        const int bi = (t & 1) ^ 1;   // holds h_{t-1}
        const int bo = t & 1;

        floatx4 acc[2][3];
#pragma unroll
        for (int jt2 = 0; jt2 < 2; jt2++) {
            acc[jt2][0] = gzx[jt2][0];
            acc[jt2][1] = gzx[jt2][1];
            floatx4 bb; bb[0] = bb[1] = bb[2] = bb[3] = bhh2[jt2];
            acc[jt2][2] = bb;
        }
#pragma unroll
        for (int kc = 0; kc < 4; kc++) {
            short8 am = *(const short8*)(&s.h[bi][wm * 16 + c][kc * 32 + quad * 8]);
#pragma unroll
            for (int jt2 = 0; jt2 < 2; jt2++)
#pragma unroll
                for (int g = 0; g < 3; g++)
                    acc[jt2][g] = __builtin_amdgcn_mfma_f32_16x16x32_bf16(
                        am, Wb[jt2][g][kc], acc[jt2][g], 0, 0, 0);
        }
        {
            short8 am4 = {0, 0, 0, 0, 0, 0, 0, 0};
            if (quad == 0) {
                short4_t e = *(const short4_t*)(&s.ext[t][wm * 16 + c][0]);
                am4[0] = e[0]; am4[1] = e[1]; am4[2] = e[2]; am4[3] = e[3];
            }
#pragma unroll
            for (int jt2 = 0; jt2 < 2; jt2++)
#pragma unroll
                for (int g = 0; g < 2; g++)
                    acc[jt2][g] = __builtin_amdgcn_mfma_f32_16x16x32_bf16(
                        am4, Wb4[jt2][g], acc[jt2][g], 0, 0, 0);
        }

        // heads for step t-1 (reads buf bi) overlap with this step's compute
        if (t > 0 && tid < 128) heads_out<FUSED>(s, p, rows0, t - 1, bi, tid);

        // gates + h update -> buf bo
#pragma unroll
        for (int r = 0; r < 4; r++) {
            const int mrow = wm * 16 + quad * 4 + r;
            short4_t e4 = *(const short4_t*)(&s.ext[t][mrow][0]);
            float a0v = bfraw2f((unsigned short)e4[0]);
            float a1v = bfraw2f((unsigned short)e4[1]);
            float s0v = bfraw2f((unsigned short)e4[2]);
            float s1v = bfraw2f((unsigned short)e4[3]);
#pragma unroll
            for (int jt2 = 0; jt2 < 2; jt2++) {
                float rr = sigm(acc[jt2][0][r]);
                float zg = sigm(acc[jt2][1][r]);
                float tn = a0v * Wa2[jt2][0] + a1v * Wa2[jt2][1]
                         + s0v * Ws2[jt2][0] + s1v * Ws2[jt2][1];
                float narg = gzx[jt2][2][r] + tn + rr * acc[jt2][2][r];
                float nn = tanh_f(narg);
                float hv = nn + zg * (hreg[jt2][r] - nn);
                hreg[jt2][r] = hv;
                s.h[bo][mrow][jb + jt2 * 16 + c] = f2bf(hv);
            }
        }
        barrier_lgkm();
    }
    if (tid < 128) heads_out<FUSED>(s, p, rows0, TT - 1, (TT - 1) & 1, tid);
}

extern "C" void kernel_launch(void* const* d_in, const int* in_sizes, int n_in,
                              void* d_out, int out_size, void* d_ws, size_t ws_size,
                              hipStream_t stream) {
    GP p;
    p.lst  = (const float*)d_in[0];
    p.lpos = (const float*)d_in[1];
    p.enc  = (const float*)d_in[2];
    p.zz   = (const float*)d_in[3];
    p.sg   = (const float*)d_in[4];
    p.fut  = (const float*)d_in[5];
    p.upd  = (const int*)d_in[6];
    p.Wdec = (const float*)d_in[7];
    p.bdec = (const float*)d_in[8];
    p.Wtv  = (const float*)d_in[9];
    p.btv  = (const float*)d_in[10];
    p.Wih  = (const float*)d_in[11];
    p.bih  = (const float*)d_in[12];
    p.Whh  = (const float*)d_in[13];
    p.bhh  = (const float*)d_in[14];
    p.Wmu  = (const float*)d_in[15];
    p.bmu  = (const float*)d_in[16];
    p.Wstd = (const float*)d_in[17];
    p.bstd = (const float*)d_in[18];
    p.Wsg  = (const float*)d_in[19];
    p.bsg  = (const float*)d_in[20];
    p.out  = (float*)d_out;
    p.P    = nullptr;

    const size_t needP = (size_t)BN * PLD * sizeof(bf16);   // 16.78 MB
    if (ws_size >= needP) {
        bf16* P = (bf16*)d_ws;
        p.P = P;
        k_gemm<<<dim3(128, 4), 512, 0, stream>>>(p.enc, p.zz, p.Wih, p.Wdec, P);
        k_gru<0><<<512, 512, 0, stream>>>(p);
    } else {
        k_gru<1><<<512, 512, 0, stream>>>(p);
    }
}